// Round 13
// baseline (169.863 us; speedup 1.0000x reference)
//
#include <hip/hip_runtime.h>
#include <math.h>

#define N_Q 4096
#define L_K 64
#define M_D 256
#define NNZ_ROWS 100000

typedef float f32x16 __attribute__((ext_vector_type(16)));
typedef __bf16 b16x8 __attribute__((ext_vector_type(8)));
union F8 { uint4 u; unsigned short s[8]; b16x8 v; };

__device__ __forceinline__ unsigned short f2bf(float x) {
  unsigned u = __float_as_uint(x);
  return (unsigned short)((u + 0x7fffu + ((u >> 16) & 1u)) >> 16);  // RNE
}

// ---- k_img: sv f32 -> bf16 image (linear, coalesced; L3-resident afterwards) ----
__global__ __launch_bounds__(256) void k_img(const float* __restrict__ sv,
                                             unsigned short* __restrict__ img) {
  const int s = blockIdx.x * 256 + threadIdx.x;   // 3,200,000 slots of 8 elems
  const int r = s >> 5, k0 = (s & 31) << 3;
  const float* rp = sv + (size_t)r * 256 + k0;
  float4 f0 = *(const float4*)rp;
  float4 f1 = *(const float4*)(rp + 4);
  F8 pk;
  pk.s[0] = f2bf(f0.x); pk.s[1] = f2bf(f0.y); pk.s[2] = f2bf(f0.z); pk.s[3] = f2bf(f0.w);
  pk.s[4] = f2bf(f1.x); pk.s[5] = f2bf(f1.y); pk.s[6] = f2bf(f1.z); pk.s[7] = f2bf(f1.w);
  *(uint4*)(img + (size_t)r * 256 + k0) = pk.u;
}

// ---- k_prep: spec detect, out2 echo, per-n packed lists, Wv^T, Wk frag image ----
__global__ __launch_bounds__(256) void k_prep(const unsigned char* __restrict__ raw,
                                              float* __restrict__ out2,
                                              const float* __restrict__ wv,
                                              float* __restrict__ wvt,
                                              const float* __restrict__ wk,
                                              unsigned short* __restrict__ wkf,
                                              const int* __restrict__ lin,
                                              int* __restrict__ pcnt,
                                              int* __restrict__ plin,
                                              unsigned char* __restrict__ pl) {
  __shared__ int pll_s[256];
  __shared__ unsigned char pls_s[256];
  __shared__ int pc_s[4];
  const int tid = threadIdx.x, lane = tid & 63;
  pll_s[tid] = 0;
  pls_s[tid] = 0;
  int v = 0;
  for (int i = tid; i < 4096; i += 256)
    if (i & 3) v |= raw[i];
  int f = __syncthreads_or(v);    // 1 = byte layout, 0 = int32 layout
  const int gi = blockIdx.x * 256 + tid;          // covers N*L; wave = one n
  bool b = f ? (raw[gi] != 0) : (((const int*)raw)[gi] != 0);
  out2[gi] = b ? 1.0f : 0.0f;
  int li = lin[gi];
  unsigned long long mask = __ballot(b);
  if (b) {
    int rank = __popcll(mask & ((1ull << lane) - 1));
    pll_s[(tid & 192) + rank] = li;
    pls_s[(tid & 192) + rank] = (unsigned char)lane;
  }
  if (lane == 0) pc_s[tid >> 6] = __popcll(mask);
  __syncthreads();
  plin[gi] = pll_s[tid];
  pl[gi] = pls_s[tid];
  if (tid < 4) pcnt[blockIdx.x * 4 + tid] = pc_s[tid];

  if (gi < 65536) {
    wvt[(gi & 255) * 256 + (gi >> 8)] = wv[gi];   // wvt[j][m] = wv[m][j]
    // A-frag image for mfma_32x32x16_bf16 (R5/R9/R10-verified lane order)
    int oc = gi >> 8, k = gi & 255;
    int tt = oc >> 5, c32o = oc & 31;
    int ks = k >> 4, kg2 = (k >> 3) & 1, j = k & 7;
    wkf[(((tt * 16 + ks) << 6) + kg2 * 32 + c32o) * 8 + j] = f2bf(wk[gi]);
  }
}

// ---- k_fused5: 4 n per block (sequential), DMA double-buffered G staging.
// 256 thr (4 waves), LDS 73.7KB -> 2 blocks/CU. Staging for n+1 in flight while
// computing n (MFMA + register RoPE + in-place softmax + V-agg from LDS tile).
#define GSTRIDE 560
#define BUF_SZ  (64 * GSTRIDE)            // 35840
#define SC_OFF  (2 * BUF_SZ)              // 71680
#define LDS_SZ  (SC_OFF + 2048)           // 73728

__global__ __launch_bounds__(256, 2) void k_fused5(
    const unsigned short* __restrict__ img, const float* __restrict__ q,
    const unsigned short* __restrict__ wkf, const float* __restrict__ pos,
    const float* __restrict__ freqs, const int* __restrict__ pcnt,
    const int* __restrict__ plin, const unsigned char* __restrict__ pl,
    unsigned short* __restrict__ agg) {
  __shared__ __align__(16) char smem[LDS_SZ];
  float* sc_s = (float*)(smem + SC_OFF);         // [64][8]; softmax in-place
  const int tid = threadIdx.x, lane = tid & 63, w = tid >> 6;
  const int c32 = lane & 31, kg = lane >> 5;
  const int rt = w >> 1, ch = w & 1;
  const int n_base = blockIdx.x * 4;

  // issue DMA stage of tile n into buf (wave w -> rows w*16..w*16+15)
  auto stage = [&](int n, char* buf, int cn) {
    #pragma unroll
    for (int j = 0; j < 16; ++j) {
      const int r = w * 16 + j;                  // wave-uniform
      if (r < cn) {
        const int pv = plin[n * 64 + r];         // lane-invariant -> s_load
        const unsigned int* src =
            (const unsigned int*)((const char*)img + (size_t)pv * 512);
        __builtin_amdgcn_global_load_lds(
            (const __attribute__((address_space(1))) unsigned int*)(src + lane),
            (__attribute__((address_space(3))) unsigned int*)(buf + r * GSTRIDE), 4, 0, 0);
        __builtin_amdgcn_global_load_lds(
            (const __attribute__((address_space(1))) unsigned int*)(src + 64 + lane),
            (__attribute__((address_space(3))) unsigned int*)(buf + r * GSTRIDE + 256), 4, 0, 0);
      }
    }
  };

  char* gcur = smem;
  char* gnxt = smem + BUF_SZ;
  int cn_cur = pcnt[n_base];
  stage(n_base, gcur, cn_cur);
  asm volatile("s_waitcnt vmcnt(0)" ::: "memory");
  __syncthreads();

  #pragma unroll
  for (int it = 0; it < 4; ++it) {
    const int n = n_base + it;
    const int cn_next = (it < 3) ? pcnt[n + 1] : 0;
    if (it < 3) stage(n + 1, gnxt, cn_next);     // lands under this tile's compute

    const int ntiles = (cn_cur + 31) >> 5;       // 0, 1 or 2 row-tiles

    // ---- K-proj MFMA + in-register RoPE (R11-verified core; linear rows) ----
    if (rt < ntiles) {
      f32x16 acc[4];
      #pragma unroll
      for (int t = 0; t < 4; ++t)
        #pragma unroll
        for (int r = 0; r < 16; ++r) acc[t][r] = 0.0f;

      const char* fbase = (const char*)wkf + ch * 65536 + lane * 16;
      F8 afc[4], afn[4];
      #pragma unroll
      for (int t = 0; t < 4; ++t) afc[t].u = *(const uint4*)(fbase + (t * 16) * 1024);

      #pragma unroll
      for (int ks = 0; ks < 16; ++ks) {
        if (ks < 15) {
          #pragma unroll
          for (int t = 0; t < 4; ++t)
            afn[t].u = *(const uint4*)(fbase + (t * 16 + ks + 1) * 1024);
        }
        F8 bf;
        bf.u = *(const uint4*)(gcur + (rt * 32 + c32) * GSTRIDE + ((ks << 1) + kg) * 16);
        #pragma unroll
        for (int t = 0; t < 4; ++t)
          acc[t] = __builtin_amdgcn_mfma_f32_32x32x16_bf16(afc[t].v, bf.v, acc[t], 0, 0, 0);
        #pragma unroll
        for (int t = 0; t < 4; ++t) afc[t] = afn[t];
      }

      const int p = rt * 32 + c32;               // lane-owned packed row
      const bool pv = p < cn_cur;
      const int pe2 = pv ? p : (cn_cur > 0 ? cn_cur - 1 : 0);
      const int l = pl[n * 64 + pe2];
      const float* lp = pos + ((size_t)n * 64 + l) * 3;
      const float pp0 = lp[0], pp1 = lp[1], pp2 = lp[2];
      #pragma unroll
      for (int t = 0; t < 4; ++t) {
        const int h = ch * 4 + t;
        const float* qh = q + (size_t)n * 256 + h * 32;
        const float* F = freqs + h * 16;
        float s = 0.f;
        #pragma unroll
        for (int g = 0; g < 4; ++g) {
          #pragma unroll
          for (int pr = 0; pr < 2; ++pr) {
            const int d0 = g * 8 + kg * 4 + pr * 2;
            const int jj = d0 >> 1;
            const int r = g * 4 + pr * 2;        // D row of reg r == d0
            float ke = acc[t][r], ko = acc[t][r + 1];
            float ang = pp0 * F[jj] + pp1 * F[128 + jj] + pp2 * F[256 + jj];
            float sn = __sinf(ang), cs = __cosf(ang);
            float2 qq = *(const float2*)(qh + d0);
            s += ke * (cs * qq.x + sn * qq.y) + ko * (cs * qq.y - sn * qq.x);
          }
        }
        s += __shfl_xor(s, 32);
        if (kg == 0 && pv) sc_s[p * 8 + h] = s * 0.0625f;   // 1/sqrt(256)
      }
    }
    __syncthreads();

    // ---- softmax in place (sc_s -> attn): 8 heads, 2 per wave ----
    #pragma unroll
    for (int uu = 0; uu < 2; ++uu) {
      const int h = w * 2 + uu;
      const bool vl = lane < cn_cur;
      float v = vl ? sc_s[lane * 8 + h] : -__builtin_inff();
      float mx = v;
      #pragma unroll
      for (int o = 32; o; o >>= 1) mx = fmaxf(mx, __shfl_xor(mx, o));
      float e = vl ? __expf(v - mx) : 0.f;
      float sm = e;
      #pragma unroll
      for (int o = 32; o; o >>= 1) sm += __shfl_xor(sm, o);
      if (vl) sc_s[lane * 8 + h] = e / sm;       // cn>=1 when vl
    }
    __syncthreads();

    // ---- V-agg from the SAME G tile (linear rows, conflict-free u16) ----
    const int m = tid;
    float ga[8];
    #pragma unroll
    for (int h = 0; h < 8; ++h) ga[h] = 0.f;
    #pragma unroll 4
    for (int p2 = 0; p2 < cn_cur; ++p2) {
      unsigned short us = *(const unsigned short*)(gcur + p2 * GSTRIDE + m * 2);
      float gv = __uint_as_float((unsigned)us << 16);
      const float4* ap = (const float4*)(sc_s + p2 * 8);     // broadcast
      float4 aA = ap[0], aB = ap[1];
      ga[0] += aA.x * gv; ga[1] += aA.y * gv; ga[2] += aA.z * gv; ga[3] += aA.w * gv;
      ga[4] += aB.x * gv; ga[5] += aB.y * gv; ga[6] += aB.z * gv; ga[7] += aB.w * gv;
    }
    #pragma unroll
    for (int h = 0; h < 8; ++h)
      agg[(size_t)n * 2048 + h * 256 + m] = f2bf(ga[h]);

    asm volatile("s_waitcnt vmcnt(0)" ::: "memory");   // next tile's DMA landed
    __syncthreads();                                    // + sc_s safe to reuse
    char* tpp = gcur; gcur = gnxt; gnxt = tpp;
    cn_cur = cn_next;
  }
}

// ---- k_out: out[n,m] = sum_j agg[n, h(m), j] * Wv[m, j]; 4 n per block ----
__global__ __launch_bounds__(256) void k_out(const unsigned short* __restrict__ agg,
                                             const float* __restrict__ wvt,
                                             float* __restrict__ out) {
  __shared__ float a_s[4][8][260];                // +4 pad
  const int tid = threadIdx.x;
  const int n0 = blockIdx.x * 4;
  #pragma unroll
  for (int it = 0; it < 4; ++it) {
    uint4 v = *(const uint4*)(agg + (size_t)(n0 + it) * 2048 + tid * 8);
    const unsigned short* sp = (const unsigned short*)&v;
    const int hh = tid >> 5, m0 = (tid & 31) * 8;
    #pragma unroll
    for (int k2 = 0; k2 < 8; ++k2)
      a_s[it][hh][m0 + k2] = __uint_as_float((unsigned)sp[k2] << 16);
  }
  __syncthreads();
  const int m = tid, h = m >> 5;
  float o0 = 0.f, o1 = 0.f, o2 = 0.f, o3 = 0.f;
  #pragma unroll 8
  for (int j = 0; j < 256; ++j) {
    float wvv = wvt[j * 256 + m];                 // coalesced, L2-hot
    o0 += a_s[0][h][j] * wvv;
    o1 += a_s[1][h][j] * wvv;
    o2 += a_s[2][h][j] * wvv;
    o3 += a_s[3][h][j] * wvv;
  }
  out[(n0 + 0) * 256 + m] = o0;
  out[(n0 + 1) * 256 + m] = o1;
  out[(n0 + 2) * 256 + m] = o2;
  out[(n0 + 3) * 256 + m] = o3;
}

extern "C" void kernel_launch(void* const* d_in, const int* in_sizes, int n_in,
                              void* d_out, int out_size, void* d_ws, size_t ws_size,
                              hipStream_t stream) {
  const float* sv  = (const float*)d_in[0];
  const int* lin   = (const int*)d_in[1];
  const unsigned char* raw = (const unsigned char*)d_in[2];
  const float* q   = (const float*)d_in[3];
  const float* wk  = (const float*)d_in[4];
  const float* wv  = (const float*)d_in[5];
  const float* pos = (const float*)d_in[6];
  const float* fq  = (const float*)d_in[7];
  float* out = (float*)d_out;
  char* ws = (char*)d_ws;

  float* wvt          = (float*)ws;                        // 262144
  unsigned short* wkf = (unsigned short*)(ws + 262144);    // 131072
  int* pcnt           = (int*)(ws + 393216);               // 16384
  int* plin           = (int*)(ws + 409600);               // 1048576
  unsigned char* pl   = (unsigned char*)(ws + 1458176);    // 262144
  unsigned short* agg = (unsigned short*)(ws + 1720320);   // 16777216
  unsigned short* img = (unsigned short*)(ws + 18497536);  // 51200000 -> ~69.7MB

  k_img   <<<12500, 256, 0, stream>>>(sv, img);
  k_prep  <<<1024, 256, 0, stream>>>(raw, out + N_Q * M_D, wv, wvt, wk, wkf,
                                     lin, pcnt, plin, pl);
  k_fused5<<<1024, 256, 0, stream>>>(img, q, wkf, pos, fq, pcnt, plin, pl, agg);
  k_out   <<<1024, 256, 0, stream>>>(agg, wvt, out);
}

// Round 14
// 120.020 us; speedup vs baseline: 1.4153x; 1.4153x over previous
//
#include <hip/hip_runtime.h>
#include <math.h>

#define N_Q 4096
#define L_K 64
#define M_D 256

typedef float f32x16 __attribute__((ext_vector_type(16)));
typedef __bf16 b16x8 __attribute__((ext_vector_type(8)));
union F8 { uint4 u; unsigned short s[8]; b16x8 v; };

__device__ __forceinline__ unsigned short f2bf(float x) {
  unsigned u = __float_as_uint(x);
  return (unsigned short)((u + 0x7fffu + ((u >> 16) & 1u)) >> 16);  // RNE
}

// ---- k_prep: spec detect, out2 echo, per-n packed lists, Wv^T, Wk frag image ----
__global__ __launch_bounds__(256) void k_prep(const unsigned char* __restrict__ raw,
                                              float* __restrict__ out2,
                                              const float* __restrict__ wv,
                                              float* __restrict__ wvt,
                                              const float* __restrict__ wk,
                                              unsigned short* __restrict__ wkf,
                                              const int* __restrict__ lin,
                                              int* __restrict__ pcnt,
                                              int* __restrict__ plin,
                                              unsigned char* __restrict__ pl) {
  __shared__ int pll_s[256];
  __shared__ unsigned char pls_s[256];
  __shared__ int pc_s[4];
  const int tid = threadIdx.x, lane = tid & 63;
  pll_s[tid] = 0;
  pls_s[tid] = 0;
  int v = 0;
  for (int i = tid; i < 4096; i += 256)
    if (i & 3) v |= raw[i];
  int f = __syncthreads_or(v);    // 1 = byte layout, 0 = int32 layout
  const int gi = blockIdx.x * 256 + tid;          // covers N*L; wave = one n
  bool b = f ? (raw[gi] != 0) : (((const int*)raw)[gi] != 0);
  out2[gi] = b ? 1.0f : 0.0f;
  int li = lin[gi];
  unsigned long long mask = __ballot(b);
  if (b) {
    int rank = __popcll(mask & ((1ull << lane) - 1));
    pll_s[(tid & 192) + rank] = li;
    pls_s[(tid & 192) + rank] = (unsigned char)lane;
  }
  if (lane == 0) pc_s[tid >> 6] = __popcll(mask);
  __syncthreads();
  plin[gi] = pll_s[tid];
  pl[gi] = pls_s[tid];
  if (tid < 4) pcnt[blockIdx.x * 4 + tid] = pc_s[tid];

  if (gi < 65536) {
    wvt[(gi & 255) * 256 + (gi >> 8)] = wv[gi];   // wvt[j][m] = wv[m][j]
    // A-frag image for mfma_32x32x16_bf16 (R5/R9-verified lane order), head-major
    int oc = gi >> 8, k = gi & 255;
    int tt = oc >> 5, c32o = oc & 31;             // tt == head
    int ks = k >> 4, kg2 = (k >> 3) & 1, j = k & 7;
    wkf[(((tt * 16 + ks) << 6) + kg2 * 32 + c32o) * 8 + j] = f2bf(wk[gi]);
  }
}

// ---- k_fused6: 1 n per block, 1024 thr (16 waves); wave = (row-tile, head).
// acc = ONE f32x16 (16 AGPR); forced 8 waves/SIMD -> 32 waves/CU.
#define SC_OFF  32768
#define AT_OFF  (SC_OFF + 2048)
#define LDS_SZ  (AT_OFF + 2048)          // 36864 B; 2 blocks/CU (wave-limited)

__global__ __launch_bounds__(1024, 8) void k_fused6(
    const float* __restrict__ sv, const float* __restrict__ q,
    const unsigned short* __restrict__ wkf, const float* __restrict__ pos,
    const float* __restrict__ freqs, const int* __restrict__ pcnt,
    const int* __restrict__ plin, const unsigned char* __restrict__ pl,
    unsigned short* __restrict__ agg) {
  __shared__ __align__(16) char smem[LDS_SZ];
  float* sc_s   = (float*)(smem + SC_OFF);       // [64][8]
  float* attn_s = (float*)(smem + AT_OFF);       // [64][8]
  const int tid = threadIdx.x, lane = tid & 63, w = tid >> 6;
  const int c32 = lane & 31, kg = lane >> 5;
  const int hd = w & 7, rt = w >> 3;             // wave = (row-tile rt, head hd)
  const int n = blockIdx.x;
  const int cnt = pcnt[n];

  if (cnt == 0) {                                 // empty n: zero agg, exit
    if (tid < 512)
      *(uint4*)((char*)agg + (size_t)n * 4096 + tid * 8) = uint4{0, 0, 0, 0};
    return;
  }
  const int ntiles = (cnt + 31) >> 5;             // 1 or 2
  const int nrows = ntiles << 5;

  // ---- stage rows coalesced: 32 rows/pass (1024 thr), clamped pad slots ----
  {
    const int r0 = tid >> 5, ii = tid & 31;
    #pragma unroll
    for (int pp = 0; pp < 2; ++pp) {
      const int rloc = pp * 32 + r0;
      if (rloc < nrows) {
        const int pe = (rloc < cnt) ? rloc : (cnt - 1);
        const float* rp = sv + (size_t)plin[n * 64 + pe] * 256 + ii * 8;
        float4 f0 = *(const float4*)rp;
        float4 f1 = *(const float4*)(rp + 4);
        F8 pk;
        pk.s[0] = f2bf(f0.x); pk.s[1] = f2bf(f0.y); pk.s[2] = f2bf(f0.z); pk.s[3] = f2bf(f0.w);
        pk.s[4] = f2bf(f1.x); pk.s[5] = f2bf(f1.y); pk.s[6] = f2bf(f1.z); pk.s[7] = f2bf(f1.w);
        *(uint4*)(smem + rloc * 512 + ((ii ^ (rloc & 31)) << 4)) = pk.u;
      }
    }
  }

  // ---- hoist RoPE meta (hides under staging/barrier) ----
  const int p = (rt << 5) + c32;                  // lane-owned packed row
  const bool pv = (rt < ntiles) && (p < cnt);
  const int pe2 = pv ? p : 0;
  const int l = pl[n * 64 + pe2];
  const float* lp = pos + ((size_t)n * 64 + l) * 3;
  const float pp0 = lp[0], pp1 = lp[1], pp2 = lp[2];

  __syncthreads();

  // ---- K-proj MFMA (one head, one row-tile) + in-register RoPE ----
  if (rt < ntiles) {
    f32x16 acc;
    #pragma unroll
    for (int r = 0; r < 16; ++r) acc[r] = 0.0f;

    const char* fb = (const char*)wkf + (hd << 14) + lane * 16;   // head hd stream
    F8 afc, afn;
    afc.u = *(const uint4*)fb;
    #pragma unroll
    for (int ks = 0; ks < 16; ++ks) {
      if (ks < 15) afn.u = *(const uint4*)(fb + (ks + 1) * 1024);
      F8 bf;
      bf.u = *(const uint4*)(smem + ((rt << 5) + c32) * 512 + ((((ks << 1) + kg) ^ c32) << 4));
      acc = __builtin_amdgcn_mfma_f32_32x32x16_bf16(afc.v, bf.v, acc, 0, 0, 0);
      afc = afn;
    }

    const float* qh = q + (size_t)n * 256 + hd * 32;
    const float* F = freqs + hd * 16;
    float s = 0.f;
    #pragma unroll
    for (int g = 0; g < 4; ++g) {
      #pragma unroll
      for (int pr = 0; pr < 2; ++pr) {
        const int d0 = g * 8 + kg * 4 + pr * 2;
        const int jj = d0 >> 1;
        const int r = g * 4 + pr * 2;             // D row of reg r == d0
        float ke = acc[r], ko = acc[r + 1];
        float ang = pp0 * F[jj] + pp1 * F[128 + jj] + pp2 * F[256 + jj];
        float sn = __sinf(ang), cs = __cosf(ang);
        float2 qq = *(const float2*)(qh + d0);
        s += ke * (cs * qq.x + sn * qq.y) + ko * (cs * qq.y - sn * qq.x);
      }
    }
    s += __shfl_xor(s, 32);
    if (kg == 0 && pv) sc_s[p * 8 + hd] = s * 0.0625f;   // 1/sqrt(256)
  }
  __syncthreads();

  // ---- softmax: 8 heads, waves 0..7 (one unit each) ----
  if (w < 8) {
    const bool vl = lane < cnt;
    float v = vl ? sc_s[lane * 8 + w] : -__builtin_inff();
    float mx = v;
    #pragma unroll
    for (int o = 32; o; o >>= 1) mx = fmaxf(mx, __shfl_xor(mx, o));
    float e = vl ? __expf(v - mx) : 0.f;
    float sm = e;
    #pragma unroll
    for (int o = 32; o; o >>= 1) sm += __shfl_xor(sm, o);
    if (vl) attn_s[lane * 8 + w] = e / sm;        // cnt>=1 -> sm>0
  }
  __syncthreads();

  // ---- V-agg from the SAME G tile: thread (m, 2-head group); broadcast attn ----
  const int m = tid & 255, hh = tid >> 8;         // hh in [0,4): heads hh*2, hh*2+1
  float g0 = 0.f, g1 = 0.f;
  #pragma unroll 4
  for (int p2 = 0; p2 < cnt; ++p2) {
    unsigned short us = *(const unsigned short*)(smem + p2 * 512 +
                        ((((m >> 3) ^ (p2 & 31)) << 4) | ((m & 7) << 1)));
    float gv = __uint_as_float((unsigned)us << 16);
    float2 a = *(const float2*)(attn_s + p2 * 8 + hh * 2);   // wave-uniform bcast
    g0 += a.x * gv;
    g1 += a.y * gv;
  }
  agg[(size_t)n * 2048 + (hh * 2) * 256 + m]     = f2bf(g0);
  agg[(size_t)n * 2048 + (hh * 2 + 1) * 256 + m] = f2bf(g1);
}

// ---- k_out: out[n,m] = sum_j agg[n, h(m), j] * Wv[m, j]; 4 n per block ----
__global__ __launch_bounds__(256) void k_out(const unsigned short* __restrict__ agg,
                                             const float* __restrict__ wvt,
                                             float* __restrict__ out) {
  __shared__ float a_s[4][8][260];                // +4 pad
  const int tid = threadIdx.x;
  const int n0 = blockIdx.x * 4;
  #pragma unroll
  for (int it = 0; it < 4; ++it) {
    uint4 v = *(const uint4*)(agg + (size_t)(n0 + it) * 2048 + tid * 8);
    const unsigned short* sp = (const unsigned short*)&v;
    const int hh = tid >> 5, m0 = (tid & 31) * 8;
    #pragma unroll
    for (int k2 = 0; k2 < 8; ++k2)
      a_s[it][hh][m0 + k2] = __uint_as_float((unsigned)sp[k2] << 16);
  }
  __syncthreads();
  const int m = tid, h = m >> 5;
  float o0 = 0.f, o1 = 0.f, o2 = 0.f, o3 = 0.f;
  #pragma unroll 8
  for (int j = 0; j < 256; ++j) {
    float wvv = wvt[j * 256 + m];                 // coalesced, L2-hot
    o0 += a_s[0][h][j] * wvv;
    o1 += a_s[1][h][j] * wvv;
    o2 += a_s[2][h][j] * wvv;
    o3 += a_s[3][h][j] * wvv;
  }
  out[(n0 + 0) * 256 + m] = o0;
  out[(n0 + 1) * 256 + m] = o1;
  out[(n0 + 2) * 256 + m] = o2;
  out[(n0 + 3) * 256 + m] = o3;
}

extern "C" void kernel_launch(void* const* d_in, const int* in_sizes, int n_in,
                              void* d_out, int out_size, void* d_ws, size_t ws_size,
                              hipStream_t stream) {
  const float* sv  = (const float*)d_in[0];
  const int* lin   = (const int*)d_in[1];
  const unsigned char* raw = (const unsigned char*)d_in[2];
  const float* q   = (const float*)d_in[3];
  const float* wk  = (const float*)d_in[4];
  const float* wv  = (const float*)d_in[5];
  const float* pos = (const float*)d_in[6];
  const float* fq  = (const float*)d_in[7];
  float* out = (float*)d_out;
  char* ws = (char*)d_ws;

  float* wvt          = (float*)ws;                        // 262144
  unsigned short* wkf = (unsigned short*)(ws + 262144);    // 131072
  int* pcnt           = (int*)(ws + 393216);               // 16384
  int* plin           = (int*)(ws + 409600);               // 1048576
  unsigned char* pl   = (unsigned char*)(ws + 1458176);    // 262144
  unsigned short* agg = (unsigned short*)(ws + 1720320);   // 16777216 -> ~18.5MB

  k_prep  <<<1024, 256, 0, stream>>>(raw, out + N_Q * M_D, wv, wvt, wk, wkf,
                                     lin, pcnt, plin, pl);
  k_fused6<<<4096, 1024, 0, stream>>>(sv, q, wkf, pos, fq, pcnt, plin, pl, agg);
  k_out   <<<1024, 256, 0, stream>>>(agg, wvt, out);
}

// Round 15
// 101.845 us; speedup vs baseline: 1.6679x; 1.1785x over previous
//
#include <hip/hip_runtime.h>
#include <math.h>

#define N_Q 4096
#define L_K 64
#define M_D 256

typedef float f32x16 __attribute__((ext_vector_type(16)));
typedef __bf16 b16x8 __attribute__((ext_vector_type(8)));
union F8 { uint4 u; unsigned short s[8]; b16x8 v; };

__device__ __forceinline__ unsigned short f2bf(float x) {
  unsigned u = __float_as_uint(x);
  return (unsigned short)((u + 0x7fffu + ((u >> 16) & 1u)) >> 16);  // RNE
}

// ---- k_prep: spec detect, out2 echo, per-n packed lists, Wv^T, Wk frag image ----
__global__ __launch_bounds__(256) void k_prep(const unsigned char* __restrict__ raw,
                                              float* __restrict__ out2,
                                              const float* __restrict__ wv,
                                              float* __restrict__ wvt,
                                              const float* __restrict__ wk,
                                              unsigned short* __restrict__ wkf,
                                              const int* __restrict__ lin,
                                              int* __restrict__ pcnt,
                                              int* __restrict__ plin,
                                              unsigned char* __restrict__ pl) {
  __shared__ int pll_s[256];
  __shared__ unsigned char pls_s[256];
  __shared__ int pc_s[4];
  const int tid = threadIdx.x, lane = tid & 63;
  pll_s[tid] = 0;
  pls_s[tid] = 0;
  int v = 0;
  for (int i = tid; i < 4096; i += 256)
    if (i & 3) v |= raw[i];
  int f = __syncthreads_or(v);    // 1 = byte layout, 0 = int32 layout
  const int gi = blockIdx.x * 256 + tid;          // covers N*L; wave = one n
  bool b = f ? (raw[gi] != 0) : (((const int*)raw)[gi] != 0);
  out2[gi] = b ? 1.0f : 0.0f;
  int li = lin[gi];
  unsigned long long mask = __ballot(b);
  if (b) {
    int rank = __popcll(mask & ((1ull << lane) - 1));
    pll_s[(tid & 192) + rank] = li;
    pls_s[(tid & 192) + rank] = (unsigned char)lane;
  }
  if (lane == 0) pc_s[tid >> 6] = __popcll(mask);
  __syncthreads();
  plin[gi] = pll_s[tid];
  pl[gi] = pls_s[tid];
  if (tid < 4) pcnt[blockIdx.x * 4 + tid] = pc_s[tid];

  if (gi < 65536) {
    wvt[(gi & 255) * 256 + (gi >> 8)] = wv[gi];   // wvt[j][m] = wv[m][j]
    // A-frag image for mfma_32x32x16_bf16 (R5/R9/R10-verified lane order)
    int oc = gi >> 8, k = gi & 255;
    int tt = oc >> 5, c32o = oc & 31;
    int ks = k >> 4, kg2 = (k >> 3) & 1, j = k & 7;
    wkf[(((tt * 16 + ks) << 6) + kg2 * 32 + c32o) * 8 + j] = f2bf(wk[gi]);
  }
}

// ---- k_fused7: R11 structure + BATCHED staging (16 loads in flight per thread).
// 1 n per block, 256 thr (4 waves), 36.8KB LDS. Wave (rt,ch): 32 rows, 4 heads.
#define SC_OFF  32768
#define AT_OFF  (SC_OFF + 2048)
#define LDS_SZ  (AT_OFF + 2048)          // 36864 B

__global__ __launch_bounds__(256, 4) void k_fused7(
    const float* __restrict__ sv, const float* __restrict__ q,
    const unsigned short* __restrict__ wkf, const float* __restrict__ pos,
    const float* __restrict__ freqs, const int* __restrict__ pcnt,
    const int* __restrict__ plin, const unsigned char* __restrict__ pl,
    unsigned short* __restrict__ agg) {
  __shared__ __align__(16) char smem[LDS_SZ];
  float* sc_s   = (float*)(smem + SC_OFF);       // [64][8]
  float* attn_s = (float*)(smem + AT_OFF);       // [64][8]
  const int tid = threadIdx.x, lane = tid & 63, w = tid >> 6;
  const int c32 = lane & 31, kg = lane >> 5;
  const int rt = w >> 1, ch = w & 1;
  const int n = blockIdx.x;
  const int cnt = pcnt[n];

  if (cnt == 0) {                                 // empty n: zero agg row, exit
    *(uint4*)((char*)agg + (size_t)n * 4096 + tid * 16) = uint4{0, 0, 0, 0};
    return;
  }
  const int ct32 = (cnt + 31) & ~31;              // 32 or 64
  const int ntiles = ct32 >> 5;

  // ---- BATCHED staging: all index loads, then all 16 row loads, then convert ----
  {
    const int r0 = tid >> 5, ii = tid & 31;       // thread: rows r0+8*pp, chunk ii
    const float* rp[8];
    #pragma unroll
    for (int pp = 0; pp < 8; ++pp) {              // 8 independent plin loads (L1/L2)
      const int rloc = pp * 8 + r0;
      const int pe = (rloc < cnt) ? rloc : (cnt - 1);
      rp[pp] = sv + (size_t)plin[n * 64 + pe] * 256 + ii * 8;
    }
    float4 fa[8], fb2[8];
    #pragma unroll
    for (int pp = 0; pp < 8; ++pp) {              // 16 dwordx4 in flight
      const int rloc = pp * 8 + r0;
      if (rloc < ct32) {
        fa[pp]  = *(const float4*)(rp[pp]);
        fb2[pp] = *(const float4*)(rp[pp] + 4);
      }
    }
    #pragma unroll
    for (int pp = 0; pp < 8; ++pp) {              // single drain, then convert+write
      const int rloc = pp * 8 + r0;
      if (rloc < ct32) {
        F8 pk;
        pk.s[0] = f2bf(fa[pp].x); pk.s[1] = f2bf(fa[pp].y);
        pk.s[2] = f2bf(fa[pp].z); pk.s[3] = f2bf(fa[pp].w);
        pk.s[4] = f2bf(fb2[pp].x); pk.s[5] = f2bf(fb2[pp].y);
        pk.s[6] = f2bf(fb2[pp].z); pk.s[7] = f2bf(fb2[pp].w);
        *(uint4*)(smem + rloc * 512 + ((ii ^ (rloc & 31)) << 4)) = pk.u;
      }
    }
  }

  // ---- hoist RoPE meta (hides under staging/barrier) ----
  const int p = rt * 32 + c32;                    // lane-owned packed row
  const bool pv = p < cnt;
  const int pe2 = pv ? p : (cnt - 1);
  const int l = pl[n * 64 + pe2];
  const float* lp = pos + ((size_t)n * 64 + l) * 3;
  const float pp0 = lp[0], pp1 = lp[1], pp2 = lp[2];

  __syncthreads();

  // ---- K-proj MFMA + in-register RoPE (R11-verified core) ----
  if (rt < ntiles) {
    f32x16 acc[4];
    #pragma unroll
    for (int t = 0; t < 4; ++t)
      #pragma unroll
      for (int r = 0; r < 16; ++r) acc[t][r] = 0.0f;

    const char* fbase = (const char*)wkf + ch * 65536 + lane * 16;
    F8 afc[4], afn[4];
    #pragma unroll
    for (int t = 0; t < 4; ++t) afc[t].u = *(const uint4*)(fbase + (t * 16) * 1024);

    #pragma unroll
    for (int ks = 0; ks < 16; ++ks) {
      if (ks < 15) {
        #pragma unroll
        for (int t = 0; t < 4; ++t)
          afn[t].u = *(const uint4*)(fbase + (t * 16 + ks + 1) * 1024);
      }
      F8 bf;
      bf.u = *(const uint4*)(smem + (rt * 32 + c32) * 512 + ((((ks << 1) + kg) ^ c32) << 4));
      #pragma unroll
      for (int t = 0; t < 4; ++t)
        acc[t] = __builtin_amdgcn_mfma_f32_32x32x16_bf16(afc[t].v, bf.v, acc[t], 0, 0, 0);
      #pragma unroll
      for (int t = 0; t < 4; ++t) afc[t] = afn[t];
    }

    #pragma unroll
    for (int t = 0; t < 4; ++t) {
      const int h = ch * 4 + t;
      const float* qh = q + (size_t)n * 256 + h * 32;
      const float* F = freqs + h * 16;
      float s = 0.f;
      #pragma unroll
      for (int g = 0; g < 4; ++g) {
        #pragma unroll
        for (int pr = 0; pr < 2; ++pr) {
          const int d0 = g * 8 + kg * 4 + pr * 2;
          const int jj = d0 >> 1;
          const int r = g * 4 + pr * 2;           // D row of reg r == d0
          float ke = acc[t][r], ko = acc[t][r + 1];
          float ang = pp0 * F[jj] + pp1 * F[128 + jj] + pp2 * F[256 + jj];
          float sn = __sinf(ang), cs = __cosf(ang);
          float2 qq = *(const float2*)(qh + d0);
          s += ke * (cs * qq.x + sn * qq.y) + ko * (cs * qq.y - sn * qq.x);
        }
      }
      s += __shfl_xor(s, 32);
      if (kg == 0 && pv) sc_s[p * 8 + h] = s * 0.0625f;   // 1/sqrt(256)
    }
  }
  __syncthreads();

  // ---- softmax: 8 heads, 2 per wave ----
  #pragma unroll
  for (int uu = 0; uu < 2; ++uu) {
    const int h = w * 2 + uu;
    const bool vl = lane < cnt;
    float v = vl ? sc_s[lane * 8 + h] : -__builtin_inff();
    float mx = v;
    #pragma unroll
    for (int o = 32; o; o >>= 1) mx = fmaxf(mx, __shfl_xor(mx, o));
    float e = vl ? __expf(v - mx) : 0.f;
    float sm = e;
    #pragma unroll
    for (int o = 32; o; o >>= 1) sm += __shfl_xor(sm, o);
    if (vl) attn_s[lane * 8 + h] = e / sm;        // cnt>=1 -> sm>0
  }
  __syncthreads();

  // ---- V-agg from the SAME G tile: thread = m; conflict-free u16 reads ----
  const int m = tid;
  float ga[8];
  #pragma unroll
  for (int h = 0; h < 8; ++h) ga[h] = 0.f;
  #pragma unroll 4
  for (int p2 = 0; p2 < cnt; ++p2) {
    unsigned short us = *(const unsigned short*)(smem + p2 * 512 +
                        ((((m >> 3) ^ (p2 & 31)) << 4) | ((m & 7) << 1)));
    float gv = __uint_as_float((unsigned)us << 16);
    const float4* ap = (const float4*)(attn_s + p2 * 8);   // broadcast
    float4 aA = ap[0], aB = ap[1];
    ga[0] += aA.x * gv; ga[1] += aA.y * gv; ga[2] += aA.z * gv; ga[3] += aA.w * gv;
    ga[4] += aB.x * gv; ga[5] += aB.y * gv; ga[6] += aB.z * gv; ga[7] += aB.w * gv;
  }
  #pragma unroll
  for (int h = 0; h < 8; ++h)
    agg[(size_t)n * 2048 + h * 256 + m] = f2bf(ga[h]);
}

// ---- k_out: out[n,m] = sum_j agg[n, h(m), j] * Wv[m, j]; 4 n per block ----
__global__ __launch_bounds__(256) void k_out(const unsigned short* __restrict__ agg,
                                             const float* __restrict__ wvt,
                                             float* __restrict__ out) {
  __shared__ float a_s[4][8][260];                // +4 pad
  const int tid = threadIdx.x;
  const int n0 = blockIdx.x * 4;
  #pragma unroll
  for (int it = 0; it < 4; ++it) {
    uint4 v = *(const uint4*)(agg + (size_t)(n0 + it) * 2048 + tid * 8);
    const unsigned short* sp = (const unsigned short*)&v;
    const int hh = tid >> 5, m0 = (tid & 31) * 8;
    #pragma unroll
    for (int k2 = 0; k2 < 8; ++k2)
      a_s[it][hh][m0 + k2] = __uint_as_float((unsigned)sp[k2] << 16);
  }
  __syncthreads();
  const int m = tid, h = m >> 5;
  float o0 = 0.f, o1 = 0.f, o2 = 0.f, o3 = 0.f;
  #pragma unroll 8
  for (int j = 0; j < 256; ++j) {
    float wvv = wvt[j * 256 + m];                 // coalesced, L2-hot
    o0 += a_s[0][h][j] * wvv;
    o1 += a_s[1][h][j] * wvv;
    o2 += a_s[2][h][j] * wvv;
    o3 += a_s[3][h][j] * wvv;
  }
  out[(n0 + 0) * 256 + m] = o0;
  out[(n0 + 1) * 256 + m] = o1;
  out[(n0 + 2) * 256 + m] = o2;
  out[(n0 + 3) * 256 + m] = o3;
}

extern "C" void kernel_launch(void* const* d_in, const int* in_sizes, int n_in,
                              void* d_out, int out_size, void* d_ws, size_t ws_size,
                              hipStream_t stream) {
  const float* sv  = (const float*)d_in[0];
  const int* lin   = (const int*)d_in[1];
  const unsigned char* raw = (const unsigned char*)d_in[2];
  const float* q   = (const float*)d_in[3];
  const float* wk  = (const float*)d_in[4];
  const float* wv  = (const float*)d_in[5];
  const float* pos = (const float*)d_in[6];
  const float* fq  = (const float*)d_in[7];
  float* out = (float*)d_out;
  char* ws = (char*)d_ws;

  float* wvt          = (float*)ws;                        // 262144
  unsigned short* wkf = (unsigned short*)(ws + 262144);    // 131072
  int* pcnt           = (int*)(ws + 393216);               // 16384
  int* plin           = (int*)(ws + 409600);               // 1048576
  unsigned char* pl   = (unsigned char*)(ws + 1458176);    // 262144
  unsigned short* agg = (unsigned short*)(ws + 1720320);   // 16777216 -> ~18.5MB

  k_prep  <<<1024, 256, 0, stream>>>(raw, out + N_Q * M_D, wv, wvt, wk, wkf,
                                     lin, pcnt, plin, pl);
  k_fused7<<<4096, 256, 0, stream>>>(sv, q, wkf, pos, fq, pcnt, plin, pl, agg);
  k_out   <<<1024, 256, 0, stream>>>(agg, wvt, out);
}